// Round 10
// baseline (567.444 us; speedup 1.0000x reference)
//
#include <hip/hip_runtime.h>
#include <hip/hip_bf16.h>
#include <stdint.h>

#define B_   8
#define C_   512
#define NPIX 4096

typedef __attribute__((ext_vector_type(8))) short bf16x8;
typedef __attribute__((ext_vector_type(4))) float f32x4;

__device__ __forceinline__ uint16_t f2bf(float f) {
    union { float f; uint32_t u; } v; v.f = f;
    uint32_t u = v.u;
    return (uint16_t)((u + 0x7FFFu + ((u >> 16) & 1u)) >> 16);
}

// pack 2 floats -> 2 bf16 in a u32 (compiler emits v_cvt_pk_bf16_f32)
__device__ __forceinline__ uint32_t pk2(float a, float b) {
    union { __hip_bfloat162 h; uint32_t u; } c;
    c.h = __float22bfloat162_rn(make_float2(a, b));
    return c.u;
}

// raw v_exp_f32 (2^x). Safe here: |x| small, no denormal/range fixup needed.
__device__ __forceinline__ float fexp2(float x) {
#if __has_builtin(__builtin_amdgcn_exp2f)
    return __builtin_amdgcn_exp2f(x);
#else
    return exp2f(x);
#endif
}

// ---------------- projection: out = W(OxC) * X(CxN) + bias, bf16 output ----
// TRANS=true : out[b][n][o]   (for q_t, k_t; O==64)
// TRANS=false: out[b][o][n]   (for v)
template<bool TRANS>
__global__ __launch_bounds__(256, 2) void proj_kernel(
    const float* __restrict__ X, const float* __restrict__ W,
    const float* __restrict__ bias, uint16_t* __restrict__ out,
    int O, float scale)
{
    __shared__ char xt[64 * 128];   // [n][c] bf16, byte = n*128 + 2c ^ ((n&7)<<4)
    const int b  = blockIdx.z;
    const int o0 = blockIdx.y * 64;
    const int n0 = blockIdx.x * 64;
    const int t = threadIdx.x, w = t >> 6, l = t & 63;
    const int l15 = l & 15, lg = l >> 4;
    const float* Xb = X + (size_t)b * C_ * NPIX + n0;

    f32x4 acc[4] = {};

    for (int cc = 0; cc < C_; cc += 64) {
        __syncthreads();
        #pragma unroll
        for (int i = 0; i < 16; i += 2) {
            int c = w * 16 + i;
            float f0 = Xb[(size_t)(cc + c) * NPIX + l];
            float f1 = Xb[(size_t)(cc + c + 1) * NPIX + l];
            uint32_t pair = pk2(f0, f1);
            int byte = (l * 128 + c * 2) ^ ((l & 7) << 4);
            *(uint32_t*)(xt + byte) = pair;
        }
        __syncthreads();
        #pragma unroll
        for (int kk = 0; kk < 2; kk++) {
            int o  = o0 + w * 16 + l15;
            int cb = cc + kk * 32 + lg * 8;
            float4 wa = *(const float4*)&W[(size_t)o * C_ + cb];
            float4 wb = *(const float4*)&W[(size_t)o * C_ + cb + 4];
            union { bf16x8 v; uint32_t u[4]; } afu;
            afu.u[0] = pk2(wa.x, wa.y); afu.u[1] = pk2(wa.z, wa.w);
            afu.u[2] = pk2(wb.x, wb.y); afu.u[3] = pk2(wb.z, wb.w);
            #pragma unroll
            for (int jt = 0; jt < 4; jt++) {
                int n = jt * 16 + l15;
                int byte = (n * 128 + (kk * 32 + lg * 8) * 2) ^ ((n & 7) << 4);
                bf16x8 bfr = *(bf16x8*)(xt + byte);
                acc[jt] = __builtin_amdgcn_mfma_f32_16x16x32_bf16(afu.v, bfr, acc[jt], 0, 0, 0);
            }
        }
    }
    int og = o0 + w * 16 + lg * 4;
    #pragma unroll
    for (int jt = 0; jt < 4; jt++) {
        int n = n0 + jt * 16 + l15;
        #pragma unroll
        for (int r = 0; r < 4; r++) {
            float v = (acc[jt][r] + bias[og + r]) * scale;
            if (TRANS) out[((size_t)b * NPIX + n) * 64 + og + r] = f2bf(v);
            else       out[((size_t)b * (size_t)O + og + r) * NPIX + n] = f2bf(v);
        }
    }
}

// ---------------- fused flash attention, no-max softmax --------------------
// r5 structure + (a) raw v_exp_f32, (b) P triple-buffer with Pcompute+pwrite
// fused PRE-barrier (safe: that buffer's readers finished one barrier ago;
// removes pk[] live-across-barrier, PV starts right after barrier),
// (c) launch_bounds(256,3) retry with the slimmer register footprint.
// Spill tripwire: WRITE_SIZE > 70MB => spilled => revert to (256,2).
__global__ __launch_bounds__(256, 3) void attn_kernel(
    const uint16_t* __restrict__ qT, const uint16_t* __restrict__ kT,
    const uint16_t* __restrict__ vB, const float* __restrict__ X,
    const float* __restrict__ gamma_p, float* __restrict__ out)
{
    __shared__ char  Pl[3][64 * 128];   // P[i][j] bf16, byte=i*128+2j ^ ((i&7)<<4)
    __shared__ float lsum[64][5];       // final l merge, padded stride 5

    const int id  = blockIdx.x;
    const int xcd = id & 7, slot = id >> 3;
    const int g   = xcd + 8 * (slot >> 6);     // 16 groups of 64 blocks per XCD
    const int qt  = slot & 63;
    const int b   = g >> 1, cb = g & 1;
    const int i0  = qt * 64;

    const int t = threadIdx.x, w = t >> 6, l = t & 63;
    const int l15 = l & 15, lg = l >> 4;
    const int c0 = cb * 256 + w * 64;

    // LDS-only barrier: waves' ds ops visible; global loads NOT drained.
    auto barrier_lds = [&]() {
        asm volatile("s_waitcnt lgkmcnt(0)" ::: "memory");
        __builtin_amdgcn_s_barrier();
    };

    // Q fragments (B-operand of swapped QK): col i = l15, k-elems d = lg*8..
    bf16x8 q8[4][2];
    #pragma unroll
    for (int it = 0; it < 4; it++)
        #pragma unroll
        for (int kk = 0; kk < 2; kk++)
            q8[it][kk] = *(const bf16x8*)&qT[((size_t)b * NPIX + i0 + it*16 + l15) * 64 + kk*32 + lg*8];

    f32x4 oacc[4][4] = {};    // [ct][it] : O^T[c][i]
    float l_part[4] = {0.f, 0.f, 0.f, 0.f};

    const uint16_t* kTb = kT + (size_t)b * NPIX * 64;
    const uint16_t* vBb = vB + ((size_t)b * C_ + c0) * NPIX;
    const uint16_t* kROW = kTb + (size_t)(w * 16 + l15) * 64 + lg * 8;

    bf16x8 k8[2], vreg[8];
    f32x4 s[4];

    auto loadK = [&](int step) {
        const uint16_t* p = kROW + (size_t)step * (64 * 64);
        k8[0] = *(const bf16x8*)p;
        k8[1] = *(const bf16x8*)(p + 32);
    };
    auto loadV = [&](int step) {
        const uint16_t* p = vBb + step * 64 + lg * 8;
        #pragma unroll
        for (int kk = 0; kk < 2; kk++)
            #pragma unroll
            for (int ct = 0; ct < 4; ct++)
                vreg[kk*4+ct] = *(const bf16x8*)(p + (size_t)(ct*16 + l15) * NPIX + kk*32);
    };
    auto QK = [&]() {
        #pragma unroll
        for (int it = 0; it < 4; it++) s[it] = f32x4{0.f, 0.f, 0.f, 0.f};
        __builtin_amdgcn_s_setprio(1);
        #pragma unroll
        for (int kk = 0; kk < 2; kk++)
            #pragma unroll
            for (int it = 0; it < 4; it++)
                s[it] = __builtin_amdgcn_mfma_f32_16x16x32_bf16(k8[kk], q8[it][kk], s[it], 0, 0, 0);
        __builtin_amdgcn_s_setprio(0);
    };
    // P = exp2(clamp(s)); row-sum partials; pack + write straight to LDS
    auto PcomputeWrite = [&](char* Pn) {
        #pragma unroll
        for (int it = 0; it < 4; it++) {
            float e0 = fexp2(fminf(s[it][0], 60.f));
            float e1 = fexp2(fminf(s[it][1], 60.f));
            float e2 = fexp2(fminf(s[it][2], 60.f));
            float e3 = fexp2(fminf(s[it][3], 60.f));
            l_part[it] += (e0 + e1) + (e2 + e3);
            uint2 v;
            v.x = pk2(e0, e1);
            v.y = pk2(e2, e3);
            int i = it * 16 + l15;
            int byte = (i * 128 + (w * 16 + lg * 4) * 2) ^ ((i & 7) << 4);
            *(uint2*)(Pn + byte) = v;
        }
    };
    auto PV = [&](const char* P) {
        __builtin_amdgcn_s_setprio(1);
        #pragma unroll
        for (int kk = 0; kk < 2; kk++) {
            bf16x8 pb[4];
            #pragma unroll
            for (int it = 0; it < 4; it++) {
                int i = it * 16 + l15;
                int byte = (i * 128 + kk * 64 + lg * 16) ^ ((i & 7) << 4);
                pb[it] = *(const bf16x8*)(P + byte);
            }
            #pragma unroll
            for (int ct = 0; ct < 4; ct++) {
                bf16x8 v8 = vreg[kk*4 + ct];
                #pragma unroll
                for (int it = 0; it < 4; it++)
                    oacc[ct][it] = __builtin_amdgcn_mfma_f32_16x16x32_bf16(v8, pb[it], oacc[ct][it], 0, 0, 0);
            }
        }
        __builtin_amdgcn_s_setprio(0);
    };

    // ---- prologue: P(0)->buf0, P(1)->buf1; V(0), K(2) in flight ----
    loadK(0);
    QK();                     // s = S(0)
    loadK(1);
    loadV(0);
    PcomputeWrite(Pl[0]);     // P(0)
    QK();                     // s = S(1) (k8 = K(1))
    loadK(2);
    PcomputeWrite(Pl[1]);     // P(1)

    char* Pprev = Pl[0];
    char* Pcur  = Pl[1];
    char* Pnext = Pl[2];

    // ---- steady state: 1 LDS-only barrier per step ----
    #pragma unroll 1
    for (int jt_ = 1; jt_ < 64; ++jt_) {
        barrier_lds();
        PV(Pprev);                  // P(jt_-1), vreg = V(jt_-1)
        loadV(jt_);                 // in flight across next barrier
        if (jt_ < 63) {
            QK();                   // s = S(jt_+1) (k8 = K(jt_+1))
            if (jt_ < 62) loadK(jt_ + 2);
            PcomputeWrite(Pnext);   // P(jt_+1) pre-barrier into 3rd buffer
        }
        char* tmp = Pprev; Pprev = Pcur; Pcur = Pnext; Pnext = tmp;
    }
    barrier_lds();
    PV(Pprev);                      // P(63)

    // ---- final l reduction: lanes -> wave, wave -> block ----
    #pragma unroll
    for (int it = 0; it < 4; it++) {
        float v = l_part[it];
        v += __shfl_xor(v, 16);
        v += __shfl_xor(v, 32);
        if (lg == 0) lsum[it * 16 + l15][w] = v;
    }
    __syncthreads();

    // ---- epilogue: out = gamma * (O/l) + x ; coalesced along i (=n) ----
    float gamma = gamma_p[0];
    float rl[4];
    #pragma unroll
    for (int it = 0; it < 4; it++) {
        int i = it * 16 + l15;
        rl[it] = 1.0f / ((lsum[i][0] + lsum[i][1]) + (lsum[i][2] + lsum[i][3]));
    }
    #pragma unroll
    for (int ct = 0; ct < 4; ct++)
        #pragma unroll
        for (int r = 0; r < 4; r++) {
            int c = c0 + ct * 16 + lg * 4 + r;
            #pragma unroll
            for (int it = 0; it < 4; it++) {
                int n = i0 + it * 16 + l15;
                size_t idx = ((size_t)b * C_ + c) * NPIX + n;
                out[idx] = gamma * (oacc[ct][it][r] * rl[it]) + X[idx];
            }
        }
}

extern "C" void kernel_launch(void* const* d_in, const int* in_sizes, int n_in,
                              void* d_out, int out_size, void* d_ws, size_t ws_size,
                              hipStream_t stream) {
    const float* x     = (const float*)d_in[0];
    const float* y     = (const float*)d_in[1];
    const float* z     = (const float*)d_in[2];
    const float* Wq    = (const float*)d_in[3];
    const float* bq    = (const float*)d_in[4];
    const float* Wk    = (const float*)d_in[5];
    const float* bk    = (const float*)d_in[6];
    const float* Wv    = (const float*)d_in[7];
    const float* bv    = (const float*)d_in[8];
    const float* gamma = (const float*)d_in[9];
    float* out = (float*)d_out;

    uint16_t* qT = (uint16_t*)d_ws;                       // [8][4096][64] bf16
    uint16_t* kT = qT + (size_t)B_ * NPIX * 64;           // [8][4096][64] bf16
    uint16_t* vb = kT + (size_t)B_ * NPIX * 64;           // [8][512][4096] bf16

    // q pre-scaled by log2(e) so softmax uses exp2 directly
    proj_kernel<true ><<<dim3(64, 1, 8), dim3(256), 0, stream>>>(x, Wq, bq, qT, 64, 1.4426950408889634f);
    proj_kernel<true ><<<dim3(64, 1, 8), dim3(256), 0, stream>>>(y, Wk, bk, kT, 64, 1.0f);
    proj_kernel<false><<<dim3(64, 8, 8), dim3(256), 0, stream>>>(z, Wv, bv, vb, 512, 1.0f);
    attn_kernel<<<dim3(1024), dim3(256), 0, stream>>>(qT, kT, vb, x, gamma, out);
}

// Round 11
// 425.337 us; speedup vs baseline: 1.3341x; 1.3341x over previous
//
#include <hip/hip_runtime.h>
#include <hip/hip_bf16.h>
#include <stdint.h>

#define B_   8
#define C_   512
#define NPIX 4096

typedef __attribute__((ext_vector_type(8))) short bf16x8;
typedef __attribute__((ext_vector_type(4))) float f32x4;

__device__ __forceinline__ uint16_t f2bf(float f) {
    union { float f; uint32_t u; } v; v.f = f;
    uint32_t u = v.u;
    return (uint16_t)((u + 0x7FFFu + ((u >> 16) & 1u)) >> 16);
}

// pack 2 floats -> 2 bf16 in a u32 (compiler emits v_cvt_pk_bf16_f32)
__device__ __forceinline__ uint32_t pk2(float a, float b) {
    union { __hip_bfloat162 h; uint32_t u; } c;
    c.h = __float22bfloat162_rn(make_float2(a, b));
    return c.u;
}

// raw v_exp_f32 (2^x). Safe here: inputs are small (|s| ~ O(1)), clamped.
__device__ __forceinline__ float fexp2(float x) {
#if __has_builtin(__builtin_amdgcn_exp2f)
    return __builtin_amdgcn_exp2f(x);
#else
    return exp2f(x);
#endif
}

// ---------------- projection: out = W(OxC) * X(CxN) + bias, bf16 output ----
// TRANS=true : out[b][n][o]   (for q_t, k_t; O==64)
// TRANS=false: out[b][o][n]   (for v)
template<bool TRANS>
__global__ __launch_bounds__(256, 2) void proj_kernel(
    const float* __restrict__ X, const float* __restrict__ W,
    const float* __restrict__ bias, uint16_t* __restrict__ out,
    int O, float scale)
{
    __shared__ char xt[64 * 128];   // [n][c] bf16, byte = n*128 + 2c ^ ((n&7)<<4)
    const int b  = blockIdx.z;
    const int o0 = blockIdx.y * 64;
    const int n0 = blockIdx.x * 64;
    const int t = threadIdx.x, w = t >> 6, l = t & 63;
    const int l15 = l & 15, lg = l >> 4;
    const float* Xb = X + (size_t)b * C_ * NPIX + n0;

    f32x4 acc[4] = {};

    for (int cc = 0; cc < C_; cc += 64) {
        __syncthreads();
        #pragma unroll
        for (int i = 0; i < 16; i += 2) {
            int c = w * 16 + i;
            float f0 = Xb[(size_t)(cc + c) * NPIX + l];
            float f1 = Xb[(size_t)(cc + c + 1) * NPIX + l];
            uint32_t pair = pk2(f0, f1);
            int byte = (l * 128 + c * 2) ^ ((l & 7) << 4);
            *(uint32_t*)(xt + byte) = pair;
        }
        __syncthreads();
        #pragma unroll
        for (int kk = 0; kk < 2; kk++) {
            int o  = o0 + w * 16 + l15;
            int cb = cc + kk * 32 + lg * 8;
            float4 wa = *(const float4*)&W[(size_t)o * C_ + cb];
            float4 wb = *(const float4*)&W[(size_t)o * C_ + cb + 4];
            union { bf16x8 v; uint32_t u[4]; } afu;
            afu.u[0] = pk2(wa.x, wa.y); afu.u[1] = pk2(wa.z, wa.w);
            afu.u[2] = pk2(wb.x, wb.y); afu.u[3] = pk2(wb.z, wb.w);
            #pragma unroll
            for (int jt = 0; jt < 4; jt++) {
                int n = jt * 16 + l15;
                int byte = (n * 128 + (kk * 32 + lg * 8) * 2) ^ ((n & 7) << 4);
                bf16x8 bfr = *(bf16x8*)(xt + byte);
                acc[jt] = __builtin_amdgcn_mfma_f32_16x16x32_bf16(afu.v, bfr, acc[jt], 0, 0, 0);
            }
        }
    }
    int og = o0 + w * 16 + lg * 4;
    #pragma unroll
    for (int jt = 0; jt < 4; jt++) {
        int n = n0 + jt * 16 + l15;
        #pragma unroll
        for (int r = 0; r < 4; r++) {
            float v = (acc[jt][r] + bias[og + r]) * scale;
            if (TRANS) out[((size_t)b * NPIX + n) * 64 + og + r] = f2bf(v);
            else       out[((size_t)b * (size_t)O + og + r) * NPIX + n] = f2bf(v);
        }
    }
}

// ---------------- fused flash attention, no-max softmax --------------------
// r5 structure + raw v_exp_f32 + P triple-buffer with Pcompute fused into the
// LDS write (PV starts right after the barrier; write of P(t+1) sits between
// barriers t and t+1, readers of that buffer finished before barrier t: 2-
// barrier separation => safe). launch_bounds(256,2): the (256,3) variant
// spills (r4: +28MB, r10: +21MB scratch traffic) -- do not retry.
__global__ __launch_bounds__(256, 2) void attn_kernel(
    const uint16_t* __restrict__ qT, const uint16_t* __restrict__ kT,
    const uint16_t* __restrict__ vB, const float* __restrict__ X,
    const float* __restrict__ gamma_p, float* __restrict__ out)
{
    __shared__ char  Pl[3][64 * 128];   // P[i][j] bf16, byte=i*128+2j ^ ((i&7)<<4)
    __shared__ float lsum[64][5];       // final l merge, padded stride 5

    const int id  = blockIdx.x;
    const int xcd = id & 7, slot = id >> 3;
    const int g   = xcd + 8 * (slot >> 6);     // 16 groups of 64 blocks per XCD
    const int qt  = slot & 63;
    const int b   = g >> 1, cb = g & 1;
    const int i0  = qt * 64;

    const int t = threadIdx.x, w = t >> 6, l = t & 63;
    const int l15 = l & 15, lg = l >> 4;
    const int c0 = cb * 256 + w * 64;

    // LDS-only barrier: waves' ds ops visible; global loads NOT drained.
    auto barrier_lds = [&]() {
        asm volatile("s_waitcnt lgkmcnt(0)" ::: "memory");
        __builtin_amdgcn_s_barrier();
    };

    // Q fragments (B-operand of swapped QK): col i = l15, k-elems d = lg*8..
    bf16x8 q8[4][2];
    #pragma unroll
    for (int it = 0; it < 4; it++)
        #pragma unroll
        for (int kk = 0; kk < 2; kk++)
            q8[it][kk] = *(const bf16x8*)&qT[((size_t)b * NPIX + i0 + it*16 + l15) * 64 + kk*32 + lg*8];

    f32x4 oacc[4][4] = {};    // [ct][it] : O^T[c][i]
    float l_part[4] = {0.f, 0.f, 0.f, 0.f};

    const uint16_t* kTb = kT + (size_t)b * NPIX * 64;
    const uint16_t* vBb = vB + ((size_t)b * C_ + c0) * NPIX;
    const uint16_t* kROW = kTb + (size_t)(w * 16 + l15) * 64 + lg * 8;

    bf16x8 k8[2], vreg[8];
    f32x4 s[4];

    auto loadK = [&](int step) {
        const uint16_t* p = kROW + (size_t)step * (64 * 64);
        k8[0] = *(const bf16x8*)p;
        k8[1] = *(const bf16x8*)(p + 32);
    };
    auto loadV = [&](int step) {
        const uint16_t* p = vBb + step * 64 + lg * 8;
        #pragma unroll
        for (int kk = 0; kk < 2; kk++)
            #pragma unroll
            for (int ct = 0; ct < 4; ct++)
                vreg[kk*4+ct] = *(const bf16x8*)(p + (size_t)(ct*16 + l15) * NPIX + kk*32);
    };
    auto QK = [&]() {
        #pragma unroll
        for (int it = 0; it < 4; it++) s[it] = f32x4{0.f, 0.f, 0.f, 0.f};
        __builtin_amdgcn_s_setprio(1);
        #pragma unroll
        for (int kk = 0; kk < 2; kk++)
            #pragma unroll
            for (int it = 0; it < 4; it++)
                s[it] = __builtin_amdgcn_mfma_f32_16x16x32_bf16(k8[kk], q8[it][kk], s[it], 0, 0, 0);
        __builtin_amdgcn_s_setprio(0);
    };
    // P = exp2(clamp(s)); row-sum partials; pack + write straight to LDS
    auto PcomputeWrite = [&](char* Pn) {
        #pragma unroll
        for (int it = 0; it < 4; it++) {
            float e0 = fexp2(fminf(s[it][0], 60.f));
            float e1 = fexp2(fminf(s[it][1], 60.f));
            float e2 = fexp2(fminf(s[it][2], 60.f));
            float e3 = fexp2(fminf(s[it][3], 60.f));
            l_part[it] += (e0 + e1) + (e2 + e3);
            uint2 v;
            v.x = pk2(e0, e1);
            v.y = pk2(e2, e3);
            int i = it * 16 + l15;
            int byte = (i * 128 + (w * 16 + lg * 4) * 2) ^ ((i & 7) << 4);
            *(uint2*)(Pn + byte) = v;
        }
    };
    auto PV = [&](const char* P) {
        __builtin_amdgcn_s_setprio(1);
        #pragma unroll
        for (int kk = 0; kk < 2; kk++) {
            bf16x8 pb[4];
            #pragma unroll
            for (int it = 0; it < 4; it++) {
                int i = it * 16 + l15;
                int byte = (i * 128 + kk * 64 + lg * 16) ^ ((i & 7) << 4);
                pb[it] = *(const bf16x8*)(P + byte);
            }
            #pragma unroll
            for (int ct = 0; ct < 4; ct++) {
                bf16x8 v8 = vreg[kk*4 + ct];
                #pragma unroll
                for (int it = 0; it < 4; it++)
                    oacc[ct][it] = __builtin_amdgcn_mfma_f32_16x16x32_bf16(v8, pb[it], oacc[ct][it], 0, 0, 0);
            }
        }
        __builtin_amdgcn_s_setprio(0);
    };

    // ---- prologue: P(0)->buf0, P(1)->buf1; V(0), K(2) in flight ----
    loadK(0);
    loadV(0);
    QK();                     // s = S(0)
    loadK(1);
    PcomputeWrite(Pl[0]);     // P(0)
    QK();                     // s = S(1) (k8 = K(1))
    loadK(2);
    PcomputeWrite(Pl[1]);     // P(1)

    char* Pprev = Pl[0];
    char* Pcur  = Pl[1];
    char* Pnext = Pl[2];

    // ---- steady state: 1 LDS-only barrier per step ----
    #pragma unroll 1
    for (int jt_ = 1; jt_ < 64; ++jt_) {
        barrier_lds();
        PV(Pprev);                  // P(jt_-1), vreg = V(jt_-1)
        loadV(jt_);                 // in flight across next barrier
        if (jt_ < 63) {
            QK();                   // s = S(jt_+1) (k8 = K(jt_+1))
            if (jt_ < 62) loadK(jt_ + 2);
            PcomputeWrite(Pnext);   // P(jt_+1), between barriers jt_ and jt_+1
        }
        char* tmp = Pprev; Pprev = Pcur; Pcur = Pnext; Pnext = tmp;
    }
    barrier_lds();
    PV(Pprev);                      // P(63)

    // ---- final l reduction: lanes -> wave, wave -> block ----
    #pragma unroll
    for (int it = 0; it < 4; it++) {
        float v = l_part[it];
        v += __shfl_xor(v, 16);
        v += __shfl_xor(v, 32);
        if (lg == 0) lsum[it * 16 + l15][w] = v;
    }
    __syncthreads();

    // ---- epilogue: out = gamma * (O/l) + x ; coalesced along i (=n) ----
    float gamma = gamma_p[0];
    float rl[4];
    #pragma unroll
    for (int it = 0; it < 4; it++) {
        int i = it * 16 + l15;
        rl[it] = 1.0f / ((lsum[i][0] + lsum[i][1]) + (lsum[i][2] + lsum[i][3]));
    }
    #pragma unroll
    for (int ct = 0; ct < 4; ct++)
        #pragma unroll
        for (int r = 0; r < 4; r++) {
            int c = c0 + ct * 16 + lg * 4 + r;
            #pragma unroll
            for (int it = 0; it < 4; it++) {
                int n = i0 + it * 16 + l15;
                size_t idx = ((size_t)b * C_ + c) * NPIX + n;
                out[idx] = gamma * (oacc[ct][it][r] * rl[it]) + X[idx];
            }
        }
}

extern "C" void kernel_launch(void* const* d_in, const int* in_sizes, int n_in,
                              void* d_out, int out_size, void* d_ws, size_t ws_size,
                              hipStream_t stream) {
    const float* x     = (const float*)d_in[0];
    const float* y     = (const float*)d_in[1];
    const float* z     = (const float*)d_in[2];
    const float* Wq    = (const float*)d_in[3];
    const float* bq    = (const float*)d_in[4];
    const float* Wk    = (const float*)d_in[5];
    const float* bk    = (const float*)d_in[6];
    const float* Wv    = (const float*)d_in[7];
    const float* bv    = (const float*)d_in[8];
    const float* gamma = (const float*)d_in[9];
    float* out = (float*)d_out;

    uint16_t* qT = (uint16_t*)d_ws;                       // [8][4096][64] bf16
    uint16_t* kT = qT + (size_t)B_ * NPIX * 64;           // [8][4096][64] bf16
    uint16_t* vb = kT + (size_t)B_ * NPIX * 64;           // [8][512][4096] bf16

    // q pre-scaled by log2(e) so softmax uses exp2 directly
    proj_kernel<true ><<<dim3(64, 1, 8), dim3(256), 0, stream>>>(x, Wq, bq, qT, 64, 1.4426950408889634f);
    proj_kernel<true ><<<dim3(64, 1, 8), dim3(256), 0, stream>>>(y, Wk, bk, kT, 64, 1.0f);
    proj_kernel<false><<<dim3(64, 8, 8), dim3(256), 0, stream>>>(z, Wv, bv, vb, 512, 1.0f);
    attn_kernel<<<dim3(1024), dim3(256), 0, stream>>>(qT, kT, vb, x, gamma, out);
}

// Round 12
// 361.728 us; speedup vs baseline: 1.5687x; 1.1758x over previous
//
#include <hip/hip_runtime.h>
#include <hip/hip_bf16.h>
#include <stdint.h>

#define B_   8
#define C_   512
#define NPIX 4096

typedef __attribute__((ext_vector_type(8))) short bf16x8;
typedef __attribute__((ext_vector_type(4))) float f32x4;

__device__ __forceinline__ uint16_t f2bf(float f) {
    union { float f; uint32_t u; } v; v.f = f;
    uint32_t u = v.u;
    return (uint16_t)((u + 0x7FFFu + ((u >> 16) & 1u)) >> 16);
}

// pack 2 floats -> 2 bf16 in a u32 (compiler emits v_cvt_pk_bf16_f32)
__device__ __forceinline__ uint32_t pk2(float a, float b) {
    union { __hip_bfloat162 h; uint32_t u; } c;
    c.h = __float22bfloat162_rn(make_float2(a, b));
    return c.u;
}

// raw v_exp_f32 (2^x). Safe here: inputs are small (|s| ~ O(1)), clamped.
__device__ __forceinline__ float fexp2(float x) {
#if __has_builtin(__builtin_amdgcn_exp2f)
    return __builtin_amdgcn_exp2f(x);
#else
    return exp2f(x);
#endif
}

// ---------------- projection: out = W(OxC) * X(CxN) + bias, bf16 output ----
// TRANS=true : out[b][n][o]      (for q_t, k_t; O==64; ldn ignored)
// TRANS=false: out[b][o][n] with leading dim ldn (for v; ldn=4128 pads the
//              8KB power-of-2 row stride that aliases L2 channels)
template<bool TRANS>
__global__ __launch_bounds__(256, 2) void proj_kernel(
    const float* __restrict__ X, const float* __restrict__ W,
    const float* __restrict__ bias, uint16_t* __restrict__ out,
    int O, float scale, int ldn)
{
    __shared__ char xt[64 * 128];   // [n][c] bf16, byte = n*128 + 2c ^ ((n&7)<<4)
    const int b  = blockIdx.z;
    const int o0 = blockIdx.y * 64;
    const int n0 = blockIdx.x * 64;
    const int t = threadIdx.x, w = t >> 6, l = t & 63;
    const int l15 = l & 15, lg = l >> 4;
    const float* Xb = X + (size_t)b * C_ * NPIX + n0;

    f32x4 acc[4] = {};

    for (int cc = 0; cc < C_; cc += 64) {
        __syncthreads();
        #pragma unroll
        for (int i = 0; i < 16; i += 2) {
            int c = w * 16 + i;
            float f0 = Xb[(size_t)(cc + c) * NPIX + l];
            float f1 = Xb[(size_t)(cc + c + 1) * NPIX + l];
            uint32_t pair = pk2(f0, f1);
            int byte = (l * 128 + c * 2) ^ ((l & 7) << 4);
            *(uint32_t*)(xt + byte) = pair;
        }
        __syncthreads();
        #pragma unroll
        for (int kk = 0; kk < 2; kk++) {
            int o  = o0 + w * 16 + l15;
            int cb = cc + kk * 32 + lg * 8;
            float4 wa = *(const float4*)&W[(size_t)o * C_ + cb];
            float4 wb = *(const float4*)&W[(size_t)o * C_ + cb + 4];
            union { bf16x8 v; uint32_t u[4]; } afu;
            afu.u[0] = pk2(wa.x, wa.y); afu.u[1] = pk2(wa.z, wa.w);
            afu.u[2] = pk2(wb.x, wb.y); afu.u[3] = pk2(wb.z, wb.w);
            #pragma unroll
            for (int jt = 0; jt < 4; jt++) {
                int n = jt * 16 + l15;
                int byte = (n * 128 + (kk * 32 + lg * 8) * 2) ^ ((n & 7) << 4);
                bf16x8 bfr = *(bf16x8*)(xt + byte);
                acc[jt] = __builtin_amdgcn_mfma_f32_16x16x32_bf16(afu.v, bfr, acc[jt], 0, 0, 0);
            }
        }
    }
    int og = o0 + w * 16 + lg * 4;
    #pragma unroll
    for (int jt = 0; jt < 4; jt++) {
        int n = n0 + jt * 16 + l15;
        #pragma unroll
        for (int r = 0; r < 4; r++) {
            float v = (acc[jt][r] + bias[og + r]) * scale;
            if (TRANS) out[((size_t)b * NPIX + n) * 64 + og + r] = f2bf(v);
            else       out[((size_t)b * (size_t)O + og + r) * (size_t)ldn + n] = f2bf(v);
        }
    }
}

// ---------------- fused flash attention, no-max softmax --------------------
// r11 structure (shared softmax, lgkm-only barrier, P triple-buffer with
// fused Pcompute->LDS write, raw v_exp_f32, launch_bounds(256,2)).
// One change: V leading dim vld (4128) breaks the 8KB power-of-2 row stride
// whose 16-segment gathers aliased onto one L2 channel (~97 cyc/VMEM, the
// r5..r11 equilibrium).
__global__ __launch_bounds__(256, 2) void attn_kernel(
    const uint16_t* __restrict__ qT, const uint16_t* __restrict__ kT,
    const uint16_t* __restrict__ vB, const float* __restrict__ X,
    const float* __restrict__ gamma_p, float* __restrict__ out, int vld)
{
    __shared__ char  Pl[3][64 * 128];   // P[i][j] bf16, byte=i*128+2j ^ ((i&7)<<4)
    __shared__ float lsum[64][5];       // final l merge, padded stride 5

    const int id  = blockIdx.x;
    const int xcd = id & 7, slot = id >> 3;
    const int g   = xcd + 8 * (slot >> 6);     // 16 groups of 64 blocks per XCD
    const int qt  = slot & 63;
    const int b   = g >> 1, cb = g & 1;
    const int i0  = qt * 64;

    const int t = threadIdx.x, w = t >> 6, l = t & 63;
    const int l15 = l & 15, lg = l >> 4;
    const int c0 = cb * 256 + w * 64;

    // LDS-only barrier: waves' ds ops visible; global loads NOT drained.
    auto barrier_lds = [&]() {
        asm volatile("s_waitcnt lgkmcnt(0)" ::: "memory");
        __builtin_amdgcn_s_barrier();
    };

    // Q fragments (B-operand of swapped QK): col i = l15, k-elems d = lg*8..
    bf16x8 q8[4][2];
    #pragma unroll
    for (int it = 0; it < 4; it++)
        #pragma unroll
        for (int kk = 0; kk < 2; kk++)
            q8[it][kk] = *(const bf16x8*)&qT[((size_t)b * NPIX + i0 + it*16 + l15) * 64 + kk*32 + lg*8];

    f32x4 oacc[4][4] = {};    // [ct][it] : O^T[c][i]
    float l_part[4] = {0.f, 0.f, 0.f, 0.f};

    const uint16_t* kTb = kT + (size_t)b * NPIX * 64;
    const uint16_t* vBb = vB + ((size_t)b * C_ + c0) * (size_t)vld + lg * 8;
    const uint16_t* kROW = kTb + (size_t)(w * 16 + l15) * 64 + lg * 8;

    // per-lane V row offsets (loop-invariant)
    int vrow[4];
    #pragma unroll
    for (int ct = 0; ct < 4; ct++) vrow[ct] = (ct * 16 + l15) * vld;

    bf16x8 k8[2], vreg[8];
    f32x4 s[4];

    auto loadK = [&](int step) {
        const uint16_t* p = kROW + (size_t)step * (64 * 64);
        k8[0] = *(const bf16x8*)p;
        k8[1] = *(const bf16x8*)(p + 32);
    };
    auto loadV = [&](int step) {
        const uint16_t* p = vBb + step * 64;
        #pragma unroll
        for (int kk = 0; kk < 2; kk++)
            #pragma unroll
            for (int ct = 0; ct < 4; ct++)
                vreg[kk*4+ct] = *(const bf16x8*)(p + vrow[ct] + kk*32);
    };
    auto QK = [&]() {
        #pragma unroll
        for (int it = 0; it < 4; it++) s[it] = f32x4{0.f, 0.f, 0.f, 0.f};
        __builtin_amdgcn_s_setprio(1);
        #pragma unroll
        for (int kk = 0; kk < 2; kk++)
            #pragma unroll
            for (int it = 0; it < 4; it++)
                s[it] = __builtin_amdgcn_mfma_f32_16x16x32_bf16(k8[kk], q8[it][kk], s[it], 0, 0, 0);
        __builtin_amdgcn_s_setprio(0);
    };
    // P = exp2(clamp(s)); row-sum partials; pack + write straight to LDS
    auto PcomputeWrite = [&](char* Pn) {
        #pragma unroll
        for (int it = 0; it < 4; it++) {
            float e0 = fexp2(fminf(s[it][0], 60.f));
            float e1 = fexp2(fminf(s[it][1], 60.f));
            float e2 = fexp2(fminf(s[it][2], 60.f));
            float e3 = fexp2(fminf(s[it][3], 60.f));
            l_part[it] += (e0 + e1) + (e2 + e3);
            uint2 v;
            v.x = pk2(e0, e1);
            v.y = pk2(e2, e3);
            int i = it * 16 + l15;
            int byte = (i * 128 + (w * 16 + lg * 4) * 2) ^ ((i & 7) << 4);
            *(uint2*)(Pn + byte) = v;
        }
    };
    auto PV = [&](const char* P) {
        __builtin_amdgcn_s_setprio(1);
        #pragma unroll
        for (int kk = 0; kk < 2; kk++) {
            bf16x8 pb[4];
            #pragma unroll
            for (int it = 0; it < 4; it++) {
                int i = it * 16 + l15;
                int byte = (i * 128 + kk * 64 + lg * 16) ^ ((i & 7) << 4);
                pb[it] = *(const bf16x8*)(P + byte);
            }
            #pragma unroll
            for (int ct = 0; ct < 4; ct++) {
                bf16x8 v8 = vreg[kk*4 + ct];
                #pragma unroll
                for (int it = 0; it < 4; it++)
                    oacc[ct][it] = __builtin_amdgcn_mfma_f32_16x16x32_bf16(v8, pb[it], oacc[ct][it], 0, 0, 0);
            }
        }
        __builtin_amdgcn_s_setprio(0);
    };

    // ---- prologue: P(0)->buf0, P(1)->buf1; V(0), K(2) in flight ----
    loadK(0);
    loadV(0);
    QK();                     // s = S(0)
    loadK(1);
    PcomputeWrite(Pl[0]);     // P(0)
    QK();                     // s = S(1) (k8 = K(1))
    loadK(2);
    PcomputeWrite(Pl[1]);     // P(1)

    char* Pprev = Pl[0];
    char* Pcur  = Pl[1];
    char* Pnext = Pl[2];

    // ---- steady state: 1 LDS-only barrier per step ----
    #pragma unroll 1
    for (int jt_ = 1; jt_ < 64; ++jt_) {
        barrier_lds();
        PV(Pprev);                  // P(jt_-1), vreg = V(jt_-1)
        loadV(jt_);                 // in flight across next barrier
        if (jt_ < 63) {
            QK();                   // s = S(jt_+1) (k8 = K(jt_+1))
            if (jt_ < 62) loadK(jt_ + 2);
            PcomputeWrite(Pnext);   // P(jt_+1), between barriers jt_ and jt_+1
        }
        char* tmp = Pprev; Pprev = Pcur; Pcur = Pnext; Pnext = tmp;
    }
    barrier_lds();
    PV(Pprev);                      // P(63)

    // ---- final l reduction: lanes -> wave, wave -> block ----
    #pragma unroll
    for (int it = 0; it < 4; it++) {
        float v = l_part[it];
        v += __shfl_xor(v, 16);
        v += __shfl_xor(v, 32);
        if (lg == 0) lsum[it * 16 + l15][w] = v;
    }
    __syncthreads();

    // ---- epilogue: out = gamma * (O/l) + x ; coalesced along i (=n) ----
    float gamma = gamma_p[0];
    float rl[4];
    #pragma unroll
    for (int it = 0; it < 4; it++) {
        int i = it * 16 + l15;
        rl[it] = 1.0f / ((lsum[i][0] + lsum[i][1]) + (lsum[i][2] + lsum[i][3]));
    }
    #pragma unroll
    for (int ct = 0; ct < 4; ct++)
        #pragma unroll
        for (int r = 0; r < 4; r++) {
            int c = c0 + ct * 16 + lg * 4 + r;
            #pragma unroll
            for (int it = 0; it < 4; it++) {
                int n = i0 + it * 16 + l15;
                size_t idx = ((size_t)b * C_ + c) * NPIX + n;
                out[idx] = gamma * (oacc[ct][it][r] * rl[it]) + X[idx];
            }
        }
}

extern "C" void kernel_launch(void* const* d_in, const int* in_sizes, int n_in,
                              void* d_out, int out_size, void* d_ws, size_t ws_size,
                              hipStream_t stream) {
    const float* x     = (const float*)d_in[0];
    const float* y     = (const float*)d_in[1];
    const float* z     = (const float*)d_in[2];
    const float* Wq    = (const float*)d_in[3];
    const float* bq    = (const float*)d_in[4];
    const float* Wk    = (const float*)d_in[5];
    const float* bk    = (const float*)d_in[6];
    const float* Wv    = (const float*)d_in[7];
    const float* bv    = (const float*)d_in[8];
    const float* gamma = (const float*)d_in[9];
    float* out = (float*)d_out;

    uint16_t* qT = (uint16_t*)d_ws;                       // [8][4096][64] bf16
    uint16_t* kT = qT + (size_t)B_ * NPIX * 64;           // [8][4096][64] bf16
    uint16_t* vb = kT + (size_t)B_ * NPIX * 64;           // [8][512][vld] bf16

    // pad V leading dim to break 8KB L2-channel aliasing; fall back if ws small
    int vld = NPIX + 32;
    size_t need = ((size_t)B_ * NPIX * 64 * 2 + (size_t)B_ * C_ * (size_t)vld) * sizeof(uint16_t);
    if (ws_size < need) vld = NPIX;

    // q pre-scaled by log2(e) so softmax uses exp2 directly
    proj_kernel<true ><<<dim3(64, 1, 8), dim3(256), 0, stream>>>(x, Wq, bq, qT, 64, 1.4426950408889634f, 64);
    proj_kernel<true ><<<dim3(64, 1, 8), dim3(256), 0, stream>>>(y, Wk, bk, kT, 64, 1.0f, 64);
    proj_kernel<false><<<dim3(64, 8, 8), dim3(256), 0, stream>>>(z, Wv, bv, vb, 512, 1.0f, vld);
    attn_kernel<<<dim3(1024), dim3(256), 0, stream>>>(qT, kT, vb, x, gamma, out, vld);
}